// Round 1
// baseline (67.345 us; speedup 1.0000x reference)
//
#include <hip/hip_runtime.h>
#include <math.h>

#define LL 1024
#define DD 512
#define HH 256

// ws layout (floats):
//   pt  : [4][H][L]  @ 0          (4*256*1024 = 1048576)
//   pu  : [4][H][L]  @ 1048576
//   tT  : [H][L]     @ 2097152    (transposed: tT[h*L + i] = pa[i][h] + b1[h])
//   uT  : [H][L]     @ 2359296
//   sraw: [L][L]     @ 2621440
// total 3670016 floats = 14 MiB

// ---------------------------------------------------------------------------
// Kernel 1: partial GEMM. tile 64i x 64h, 4x4 per thread, K-chunk of 128.
// grid (16 i-blocks, 4 h-blocks, 4 k-chunks) = 256 blocks.
// Reads S and W1 directly from global (both L2-resident, heavy broadcast reuse).
// ---------------------------------------------------------------------------
__global__ __launch_bounds__(256) void sp_gemm_partial(
    const float* __restrict__ S, const float* __restrict__ W1,
    float* __restrict__ pt, float* __restrict__ pu) {
  const int iy = threadIdx.x & 15;
  const int hx = threadIdx.x >> 4;
  const int i0 = blockIdx.x * 64;
  const int h0 = blockIdx.y * 64;
  const int k0 = blockIdx.z * 128;

  const float* sp = S  + (size_t)(i0 + 4 * iy) * DD + k0;
  const float* wp = W1 + (size_t)(h0 + 4 * hx) * (2 * DD) + k0;

  float at[4][4] = {{0.f}};
  float au[4][4] = {{0.f}};

  #pragma unroll 2
  for (int kk = 0; kk < 128; kk += 4) {
    float4 s[4], wa[4], wb[4];
    #pragma unroll
    for (int a = 0; a < 4; ++a)
      s[a] = *(const float4*)(sp + (size_t)a * DD + kk);
    #pragma unroll
    for (int b = 0; b < 4; ++b) {
      wa[b] = *(const float4*)(wp + (size_t)b * (2 * DD) + kk);
      wb[b] = *(const float4*)(wp + (size_t)b * (2 * DD) + DD + kk);
    }
    #pragma unroll
    for (int a = 0; a < 4; ++a) {
      #pragma unroll
      for (int b = 0; b < 4; ++b) {
        at[a][b] += s[a].x * wa[b].x + s[a].y * wa[b].y +
                    s[a].z * wa[b].z + s[a].w * wa[b].w;
        au[a][b] += s[a].x * wb[b].x + s[a].y * wb[b].y +
                    s[a].z * wb[b].z + s[a].w * wb[b].w;
      }
    }
  }

  float* ptb = pt + (size_t)blockIdx.z * (HH * LL);
  float* pub = pu + (size_t)blockIdx.z * (HH * LL);
  #pragma unroll
  for (int b = 0; b < 4; ++b) {
    const int h = h0 + 4 * hx + b;
    float4 vt = make_float4(at[0][b], at[1][b], at[2][b], at[3][b]);
    float4 vu = make_float4(au[0][b], au[1][b], au[2][b], au[3][b]);
    *(float4*)(ptb + (size_t)h * LL + i0 + 4 * iy) = vt;
    *(float4*)(pub + (size_t)h * LL + i0 + 4 * iy) = vu;
  }
}

// ---------------------------------------------------------------------------
// Kernel 2: sum the 4 K-partials, add b1 into t. Outputs stay transposed.
// grid 512 x 256 threads; first 65536 float4s = t, next 65536 = u.
// ---------------------------------------------------------------------------
__global__ __launch_bounds__(256) void sp_reduce_bias(
    const float* __restrict__ pt, const float* __restrict__ pu,
    const float* __restrict__ b1,
    float* __restrict__ tT, float* __restrict__ uT) {
  const int n = blockIdx.x * 256 + threadIdx.x;   // 0..131071
  const int NT = HH * LL / 4;                     // 65536 float4s per matrix
  const bool isT = n < NT;
  const int m = isT ? n : n - NT;
  const float* p = isT ? pt : pu;

  float4 acc = make_float4(0.f, 0.f, 0.f, 0.f);
  #pragma unroll
  for (int c = 0; c < 4; ++c) {
    float4 v = *(const float4*)(p + (size_t)c * (HH * LL) + 4 * (size_t)m);
    acc.x += v.x; acc.y += v.y; acc.z += v.z; acc.w += v.w;
  }
  if (isT) {
    const float bb = b1[m >> 8];   // h = 4m / 1024
    acc.x += bb; acc.y += bb; acc.z += bb; acc.w += bb;
  }
  float* o = isT ? tT : uT;
  *(float4*)(o + 4 * (size_t)m) = acc;
}

// ---------------------------------------------------------------------------
// Kernel 3: pairwise relu-dot. tile 64x64, 4x4 per thread.
// grid (16,16) = 256 blocks = one full round on 256 CUs.
// LDS: T/U as [256 h][64+8 pad] floats -> conflict-free float4 reads.
// ---------------------------------------------------------------------------
__global__ __launch_bounds__(256) void sp_pairwise(
    const float* __restrict__ tT, const float* __restrict__ uT,
    const float* __restrict__ W2, float* __restrict__ sraw) {
  __shared__ float Tl[HH][72];
  __shared__ float Ul[HH][72];
  __shared__ float w2s[HH];

  const int tx = threadIdx.x & 15;
  const int ty = threadIdx.x >> 4;
  const int i0 = blockIdx.y * 64;
  const int j0 = blockIdx.x * 64;

  // stage: pure float4 copies (t/u already transposed in ws)
  #pragma unroll
  for (int s = 0; s < 16; ++s) {
    const int m = s * 256 + threadIdx.x;
    const int h = m >> 4;
    const int g = m & 15;
    *(float4*)&Tl[h][4 * g] = *(const float4*)(tT + (size_t)h * LL + i0 + 4 * g);
    *(float4*)&Ul[h][4 * g] = *(const float4*)(uT + (size_t)h * LL + j0 + 4 * g);
  }
  w2s[threadIdx.x] = W2[threadIdx.x];
  __syncthreads();

  float acc[4][4] = {{0.f}};

  #pragma unroll 4
  for (int h = 0; h < HH; ++h) {
    const float4 tv4 = *(const float4*)&Tl[h][4 * ty];
    const float4 uv4 = *(const float4*)&Ul[h][4 * tx];
    const float w = w2s[h];
    const float tv[4] = {tv4.x, tv4.y, tv4.z, tv4.w};
    const float uv[4] = {uv4.x, uv4.y, uv4.z, uv4.w};
    #pragma unroll
    for (int a = 0; a < 4; ++a) {
      #pragma unroll
      for (int b = 0; b < 4; ++b) {
        acc[a][b] = fmaf(fmaxf(tv[a] + uv[b], 0.f), w, acc[a][b]);
      }
    }
  }

  #pragma unroll
  for (int a = 0; a < 4; ++a) {
    float4 v = make_float4(acc[a][0], acc[a][1], acc[a][2], acc[a][3]);
    *(float4*)(sraw + (size_t)(i0 + 4 * ty + a) * LL + j0 + 4 * tx) = v;
  }
}

// ---------------------------------------------------------------------------
// Kernel 4: out = sigmoid(0.5*(s + s^T) + b2). 32x32 tiles, LDS transpose.
// ---------------------------------------------------------------------------
__global__ __launch_bounds__(256) void sp_symsig(
    const float* __restrict__ sraw, const float* __restrict__ b2,
    float* __restrict__ out) {
  __shared__ float B[32][33];
  const int i0 = blockIdx.y * 32;
  const int j0 = blockIdx.x * 32;
  const int r  = threadIdx.x >> 3;   // 0..31
  const int c8 = threadIdx.x & 7;    // 0..7

  const float4 bt = *(const float4*)(sraw + (size_t)(j0 + r) * LL + i0 + 4 * c8);
  B[r][4 * c8 + 0] = bt.x;
  B[r][4 * c8 + 1] = bt.y;
  B[r][4 * c8 + 2] = bt.z;
  B[r][4 * c8 + 3] = bt.w;
  __syncthreads();

  const float4 a = *(const float4*)(sraw + (size_t)(i0 + r) * LL + j0 + 4 * c8);
  const float bb = b2[0];
  float4 o;
  float x;
  x = 0.5f * (a.x + B[4 * c8 + 0][r]) + bb; o.x = 1.f / (1.f + expf(-x));
  x = 0.5f * (a.y + B[4 * c8 + 1][r]) + bb; o.y = 1.f / (1.f + expf(-x));
  x = 0.5f * (a.z + B[4 * c8 + 2][r]) + bb; o.z = 1.f / (1.f + expf(-x));
  x = 0.5f * (a.w + B[4 * c8 + 3][r]) + bb; o.w = 1.f / (1.f + expf(-x));
  *(float4*)(out + (size_t)(i0 + r) * LL + j0 + 4 * c8) = o;
}

// ---------------------------------------------------------------------------
extern "C" void kernel_launch(void* const* d_in, const int* in_sizes, int n_in,
                              void* d_out, int out_size, void* d_ws, size_t ws_size,
                              hipStream_t stream) {
  const float* S  = (const float*)d_in[0];   // [L, D]
  const float* W1 = (const float*)d_in[1];   // [H, 2D]
  const float* b1 = (const float*)d_in[2];   // [H]
  const float* W2 = (const float*)d_in[3];   // [1, H]
  const float* b2 = (const float*)d_in[4];   // [1]
  float* out = (float*)d_out;

  float* ws = (float*)d_ws;
  float* pt   = ws;                          // [4][H][L]
  float* pu   = ws + 4 * HH * LL;            // [4][H][L]
  float* tT   = ws + 8 * HH * LL;            // [H][L]
  float* uT   = ws + 9 * HH * LL;            // [H][L]
  float* sraw = ws + 10 * HH * LL;           // [L][L]

  hipLaunchKernelGGL(sp_gemm_partial, dim3(16, 4, 4), dim3(256), 0, stream,
                     S, W1, pt, pu);
  hipLaunchKernelGGL(sp_reduce_bias, dim3(512), dim3(256), 0, stream,
                     pt, pu, b1, tT, uT);
  hipLaunchKernelGGL(sp_pairwise, dim3(16, 16), dim3(256), 0, stream,
                     tT, uT, W2, sraw);
  hipLaunchKernelGGL(sp_symsig, dim3(32, 32), dim3(256), 0, stream,
                     sraw, b2, out);
}